// Round 1
// baseline (2673.282 us; speedup 1.0000x reference)
//
#include <hip/hip_runtime.h>
#include <math.h>

#define B_  32
#define S_  24
#define T_  24
#define E_  620
#define H_  1000
#define HP_ 1024
#define V_  30000
#define M2_ 1000   // 2*M
#define MD_ 500    // M

// ---------------------------------------------------------------------------
// Generic tiled fp32 GEMM: C = A @ Bw^T  (A: [M,K] lda, Bw: [N,K] ldb)
// mode 0: plain row-major store C[M,N] (ldc)
// mode 2: maxout epilogue: val = acc + e1[row][col] + e2[row&31][col];
//         Tmax[row*ldc + col/2] = max(pairs)
// mode 3: output scatter: row = t*32+b -> C[(b*T_+t)*ldc + col]
// ---------------------------------------------------------------------------
struct GemmArgs {
  const float* A[8];
  const float* Bw[8];
  float*       C[8];
  int lda, ldb, ldc;
  int M, N, K;
  int mode;
  const float* e1;
  const float* e2;
};

__global__ __launch_bounds__(256) void gemm_abT(GemmArgs g) {
  __shared__ float As[32][68];
  __shared__ float Ws[32][68];
  const int z = blockIdx.z;
  const float* __restrict__ A  = g.A[z];
  const float* __restrict__ Bw = g.Bw[z];
  float* __restrict__ C        = g.C[z];
  const int tid = threadIdx.x;
  const int i0 = blockIdx.y * 64;
  const int j0 = blockIdx.x * 64;
  const int ti = tid & 15, tj = tid >> 4;
  float acc[4][4];
#pragma unroll
  for (int a = 0; a < 4; ++a)
#pragma unroll
    for (int b = 0; b < 4; ++b) acc[a][b] = 0.f;

  for (int k0 = 0; k0 < g.K; k0 += 32) {
#pragma unroll
    for (int r = 0; r < 8; ++r) {
      int idx = (r << 8) + tid;
      int kk = idx & 31, mm = idx >> 5;
      int gk = k0 + kk;
      float va = 0.f, vb = 0.f;
      if (gk < g.K) {
        int gm = i0 + mm;
        if (gm < g.M) va = A[(size_t)gm * g.lda + gk];
        int gn = j0 + mm;
        if (gn < g.N) vb = Bw[(size_t)gn * g.ldb + gk];
      }
      As[kk][mm] = va;
      Ws[kk][mm] = vb;
    }
    __syncthreads();
#pragma unroll
    for (int kk = 0; kk < 32; ++kk) {
      float4 a4 = *(const float4*)&As[kk][ti << 2];
      float4 b4 = *(const float4*)&Ws[kk][tj << 2];
      float av[4] = {a4.x, a4.y, a4.z, a4.w};
      float bv[4] = {b4.x, b4.y, b4.z, b4.w};
#pragma unroll
      for (int ii = 0; ii < 4; ++ii)
#pragma unroll
        for (int jj = 0; jj < 4; ++jj)
          acc[ii][jj] = fmaf(av[ii], bv[jj], acc[ii][jj]);
    }
    __syncthreads();
  }

  int gn = j0 + (tj << 2);
  if (gn >= g.N) return;
  if (g.mode == 0) {
#pragma unroll
    for (int ii = 0; ii < 4; ++ii) {
      int gm = i0 + (ti << 2) + ii;
      if (gm < g.M) {
        float4 o = make_float4(acc[ii][0], acc[ii][1], acc[ii][2], acc[ii][3]);
        *(float4*)&C[(size_t)gm * g.ldc + gn] = o;
      }
    }
  } else if (g.mode == 2) {
#pragma unroll
    for (int ii = 0; ii < 4; ++ii) {
      int gm = i0 + (ti << 2) + ii;
      if (gm < g.M) {
        int b = gm & 31;
        float v0 = acc[ii][0] + g.e1[(size_t)gm * M2_ + gn + 0] + g.e2[(size_t)b * M2_ + gn + 0];
        float v1 = acc[ii][1] + g.e1[(size_t)gm * M2_ + gn + 1] + g.e2[(size_t)b * M2_ + gn + 1];
        float v2 = acc[ii][2] + g.e1[(size_t)gm * M2_ + gn + 2] + g.e2[(size_t)b * M2_ + gn + 2];
        float v3 = acc[ii][3] + g.e1[(size_t)gm * M2_ + gn + 3] + g.e2[(size_t)b * M2_ + gn + 3];
        C[(size_t)gm * g.ldc + (gn >> 1)]     = fmaxf(v0, v1);
        C[(size_t)gm * g.ldc + (gn >> 1) + 1] = fmaxf(v2, v3);
      }
    }
  } else { // mode 3
#pragma unroll
    for (int ii = 0; ii < 4; ++ii) {
      int gm = i0 + (ti << 2) + ii;
      if (gm < g.M) {
        int t = gm >> 5, b = gm & 31;
        float4 o = make_float4(acc[ii][0], acc[ii][1], acc[ii][2], acc[ii][3]);
        *(float4*)&C[((size_t)b * T_ + t) * (size_t)g.ldc + gn] = o;
      }
    }
  }
}

// ---------------------------------------------------------------------------
// Embedding gather: rows r = step*32 + b
// ---------------------------------------------------------------------------
__global__ __launch_bounds__(256) void gather_emb(
    const int* __restrict__ src, const int* __restrict__ tgt,
    const float* __restrict__ semb, const float* __restrict__ temb,
    float* __restrict__ XE, float* __restrict__ YE) {
  int row = blockIdx.x;  // 0..1535
  int tid = threadIdx.x;
  int isT = row >= S_ * B_;
  int r = isT ? row - S_ * B_ : row;
  int st = r >> 5, b = r & 31;
  int tok = isT ? tgt[b * T_ + st] : src[b * S_ + st];
  const float* e = (isT ? temb : semb) + (size_t)tok * E_;
  float* o = (isT ? YE : XE) + (size_t)r * E_;
  for (int k = tid; k < E_; k += 256) o[k] = e[k];
}

// ---------------------------------------------------------------------------
// GRU phase A: pre_r = h@Ur^T, pre_z = h@Uz^T; rh = sigmoid(.)*h; zb = sigmoid(.)
// State layout: hbk [32][1024] (b-major, k padded with zeros).
// Grid: 250 blocks x 256 thr. Block owns j0=bid*4..+3. Wave w owns k quarter
// [256w,256w+256). Lane = (b in 0..31, kh in 0..1) -> 128-k slice, 32 float4.
// ---------------------------------------------------------------------------
__global__ __launch_bounds__(256) void gru_phaseA(
    const float* __restrict__ hbk,
    const float* __restrict__ Ur, const float* __restrict__ Uz,
    const float* __restrict__ Xr, const float* __restrict__ Xz,
    const float* __restrict__ cr, const float* __restrict__ cz,
    const float* __restrict__ br, const float* __restrict__ bz,
    float* __restrict__ rhbk, float* __restrict__ zb) {
  __shared__ float red[4][4][2][32];
  const int tid = threadIdx.x;
  const int w = tid >> 6;
  const int lane = tid & 63;
  const int b = lane & 31, kh = lane >> 5;
  const int j0 = blockIdx.x * 4;
  const int kbase = w * 256 + kh * 128;
  const float4* h4 = (const float4*)(hbk + b * HP_ + kbase);
  float4 accr[4], accz[4];
#pragma unroll
  for (int j = 0; j < 4; ++j) {
    accr[j] = make_float4(0.f, 0.f, 0.f, 0.f);
    accz[j] = make_float4(0.f, 0.f, 0.f, 0.f);
  }
  for (int it = 0; it < 32; ++it) {
    int k = kbase + it * 4;
    if (k < H_) {
      float4 h = h4[it];
#pragma unroll
      for (int j = 0; j < 4; ++j) {
        float4 u = *(const float4*)(Ur + (size_t)(j0 + j) * H_ + k);
        accr[j].x = fmaf(h.x, u.x, accr[j].x);
        accr[j].y = fmaf(h.y, u.y, accr[j].y);
        accr[j].z = fmaf(h.z, u.z, accr[j].z);
        accr[j].w = fmaf(h.w, u.w, accr[j].w);
        float4 v = *(const float4*)(Uz + (size_t)(j0 + j) * H_ + k);
        accz[j].x = fmaf(h.x, v.x, accz[j].x);
        accz[j].y = fmaf(h.y, v.y, accz[j].y);
        accz[j].z = fmaf(h.z, v.z, accz[j].z);
        accz[j].w = fmaf(h.w, v.w, accz[j].w);
      }
    }
  }
  float pr[4], pz[4];
#pragma unroll
  for (int j = 0; j < 4; ++j) {
    pr[j] = accr[j].x + accr[j].y + accr[j].z + accr[j].w;
    pz[j] = accz[j].x + accz[j].y + accz[j].z + accz[j].w;
    pr[j] += __shfl_xor(pr[j], 32);
    pz[j] += __shfl_xor(pz[j], 32);
  }
  if (lane < 32) {
#pragma unroll
    for (int j = 0; j < 4; ++j) {
      red[w][j][0][b] = pr[j];
      red[w][j][1][b] = pz[j];
    }
  }
  __syncthreads();
  int eb = tid & 31, eg = (tid >> 5) & 1, ej = tid >> 6;
  float s = red[0][ej][eg][eb] + red[1][ej][eg][eb] + red[2][ej][eg][eb] + red[3][ej][eg][eb];
  int j = j0 + ej;
  int o = eb * H_ + j;
  if (eg == 0) {
    float pre = s + Xr[o] + br[j] + (cr ? cr[o] : 0.f);
    float r = 1.f / (1.f + expf(-pre));
    rhbk[eb * HP_ + j] = r * hbk[eb * HP_ + j];
  } else {
    float pre = s + Xz[o] + bz[j] + (cz ? cz[o] : 0.f);
    zb[o] = 1.f / (1.f + expf(-pre));
  }
}

// ---------------------------------------------------------------------------
// GRU phase B: cand = tanh(rh@U^T + Xc + cc + bb); s = (1-z)*s + z*cand
// In-place on s_state; optional row-major copy to srm (decoder S_all slice).
// ---------------------------------------------------------------------------
__global__ __launch_bounds__(256) void gru_phaseB(
    const float* __restrict__ rhbk, const float* __restrict__ U,
    const float* __restrict__ Xc, const float* __restrict__ cc,
    const float* __restrict__ bb, const float* __restrict__ zb,
    float* s_state, float* srm) {
  __shared__ float red[4][4][32];
  const int tid = threadIdx.x;
  const int w = tid >> 6;
  const int lane = tid & 63;
  const int b = lane & 31, kh = lane >> 5;
  const int j0 = blockIdx.x * 4;
  const int kbase = w * 256 + kh * 128;
  const float4* h4 = (const float4*)(rhbk + b * HP_ + kbase);
  float4 acc[4];
#pragma unroll
  for (int j = 0; j < 4; ++j) acc[j] = make_float4(0.f, 0.f, 0.f, 0.f);
  for (int it = 0; it < 32; ++it) {
    int k = kbase + it * 4;
    if (k < H_) {
      float4 h = h4[it];
#pragma unroll
      for (int j = 0; j < 4; ++j) {
        float4 u = *(const float4*)(U + (size_t)(j0 + j) * H_ + k);
        acc[j].x = fmaf(h.x, u.x, acc[j].x);
        acc[j].y = fmaf(h.y, u.y, acc[j].y);
        acc[j].z = fmaf(h.z, u.z, acc[j].z);
        acc[j].w = fmaf(h.w, u.w, acc[j].w);
      }
    }
  }
  float p[4];
#pragma unroll
  for (int j = 0; j < 4; ++j) {
    p[j] = acc[j].x + acc[j].y + acc[j].z + acc[j].w;
    p[j] += __shfl_xor(p[j], 32);
  }
  if (lane < 32) {
#pragma unroll
    for (int j = 0; j < 4; ++j) red[w][j][b] = p[j];
  }
  __syncthreads();
  if (tid < 128) {
    int eb = tid & 31, ej = tid >> 5;
    float s = red[0][ej][eb] + red[1][ej][eb] + red[2][ej][eb] + red[3][ej][eb];
    int j = j0 + ej;
    int o = eb * H_ + j;
    float cand = tanhf(s + Xc[o] + bb[j] + (cc ? cc[o] : 0.f));
    float z = zb[o];
    float old = s_state[eb * HP_ + j];
    float nv = (1.f - z) * old + z * cand;
    s_state[eb * HP_ + j] = nv;
    if (srm) srm[o] = nv;
  }
}

// ---------------------------------------------------------------------------
// Context projections + s0: out = (tanh?)(c @ W^T), c in hbk layout.
// mode 0: row-major store [32][1000]; mode 2: tanh -> hbk2 AND Srm slice 0.
// ---------------------------------------------------------------------------
struct CtxArgs {
  const float* W[5];
  float* out[5];
  int mode[5];
  const float* x;   // hbk
  float* hbk2;
  float* srm0;
};

__global__ __launch_bounds__(256) void ctx_mv(CtxArgs a) {
  __shared__ float red[4][4][32];
  const int z = blockIdx.z;
  const float* __restrict__ W = a.W[z];
  const float* __restrict__ x = a.x;
  const int tid = threadIdx.x;
  const int w = tid >> 6;
  const int lane = tid & 63;
  const int b = lane & 31, kh = lane >> 5;
  const int j0 = blockIdx.x * 4;
  const int kbase = w * 256 + kh * 128;
  const float4* h4 = (const float4*)(x + b * HP_ + kbase);
  float4 acc[4];
#pragma unroll
  for (int j = 0; j < 4; ++j) acc[j] = make_float4(0.f, 0.f, 0.f, 0.f);
  for (int it = 0; it < 32; ++it) {
    int k = kbase + it * 4;
    if (k < H_) {
      float4 h = h4[it];
#pragma unroll
      for (int j = 0; j < 4; ++j) {
        float4 u = *(const float4*)(W + (size_t)(j0 + j) * H_ + k);
        acc[j].x = fmaf(h.x, u.x, acc[j].x);
        acc[j].y = fmaf(h.y, u.y, acc[j].y);
        acc[j].z = fmaf(h.z, u.z, acc[j].z);
        acc[j].w = fmaf(h.w, u.w, acc[j].w);
      }
    }
  }
  float p[4];
#pragma unroll
  for (int j = 0; j < 4; ++j) {
    p[j] = acc[j].x + acc[j].y + acc[j].z + acc[j].w;
    p[j] += __shfl_xor(p[j], 32);
  }
  if (lane < 32) {
#pragma unroll
    for (int j = 0; j < 4; ++j) red[w][j][b] = p[j];
  }
  __syncthreads();
  if (tid < 128) {
    int eb = tid & 31, ej = tid >> 5;
    float s = red[0][ej][eb] + red[1][ej][eb] + red[2][ej][eb] + red[3][ej][eb];
    int j = j0 + ej;
    if (a.mode[z] == 0) {
      a.out[z][eb * H_ + j] = s;
    } else {
      float v = tanhf(s);
      a.hbk2[eb * HP_ + j] = v;
      a.srm0[eb * H_ + j] = v;
    }
  }
}

// ---------------------------------------------------------------------------
// Host
// ---------------------------------------------------------------------------
extern "C" void kernel_launch(void* const* d_in, const int* in_sizes, int n_in,
                              void* d_out, int out_size, void* d_ws, size_t ws_size,
                              hipStream_t stream) {
  const int*   src     = (const int*)d_in[0];
  const int*   tgt     = (const int*)d_in[1];
  const float* src_emb = (const float*)d_in[3];
  const float* tgt_emb = (const float*)d_in[4];
  const float* enc_W   = (const float*)d_in[5];
  const float* enc_Wz  = (const float*)d_in[6];
  const float* enc_Wr  = (const float*)d_in[7];
  const float* enc_U   = (const float*)d_in[8];
  const float* enc_Uz  = (const float*)d_in[9];
  const float* enc_Ur  = (const float*)d_in[10];
  const float* enc_b   = (const float*)d_in[11];
  const float* enc_bz  = (const float*)d_in[12];
  const float* enc_br  = (const float*)d_in[13];
  const float* dec_W   = (const float*)d_in[14];
  const float* dec_Wz  = (const float*)d_in[15];
  const float* dec_Wr  = (const float*)d_in[16];
  const float* dec_U   = (const float*)d_in[17];
  const float* dec_Uz  = (const float*)d_in[18];
  const float* dec_Ur  = (const float*)d_in[19];
  const float* dec_C   = (const float*)d_in[20];
  const float* dec_Cz  = (const float*)d_in[21];
  const float* dec_Cr  = (const float*)d_in[22];
  const float* dec_b   = (const float*)d_in[23];
  const float* dec_bz  = (const float*)d_in[24];
  const float* dec_br  = (const float*)d_in[25];
  const float* W_s     = (const float*)d_in[26];
  const float* U_o     = (const float*)d_in[27];
  const float* V_o     = (const float*)d_in[28];
  const float* C_o     = (const float*)d_in[29];
  const float* W_o     = (const float*)d_in[30];
  float* out = (float*)d_out;
  float* ws  = (float*)d_ws;

  // workspace layout (floats)
  float* XE   = ws + 0;                 // 768*620
  float* YE   = ws + 476160;            // 768*620
  float* XPr  = ws + 952320;            // 768*1000 each
  float* XPz  = ws + 1720320;
  float* XPc  = ws + 2488320;
  float* YPr  = ws + 3256320;
  float* YPz  = ws + 4024320;
  float* YPc  = ws + 4792320;
  float* YV   = ws + 5560320;           // 768*1000
  float* hbk  = ws + 6328320;           // 32*1024
  float* rhbk = ws + 6361088;           // 32*1024
  float* hbk2 = ws + 6393856;           // 32*1024
  float* zb   = ws + 6426624;           // 32*1000
  float* cCr  = ws + 6458624;
  float* cCz  = ws + 6490624;
  float* cC   = ws + 6522624;
  float* cCo  = ws + 6554624;
  float* Srm  = ws + 6586624;           // 24*32*1000
  float* Tmax = ws + 7354624;           // 768*512
  (void)in_sizes; (void)n_in; (void)out_size; (void)ws_size;

  // zero state buffers (hbk, rhbk, hbk2 contiguous) — covers h0=0 and k-pads
  hipMemsetAsync(hbk, 0, 3 * HP_ * B_ * sizeof(float), stream);

  // gather embeddings
  gather_emb<<<dim3(2 * S_ * B_), dim3(256), 0, stream>>>(src, tgt, src_emb, tgt_emb, XE, YE);

  // batched input projections (7 GEMMs, M=768 K=620 N=1000)
  {
    GemmArgs g = {};
    const float* As[7] = {XE, XE, XE, YE, YE, YE, YE};
    const float* Bs[7] = {enc_Wr, enc_Wz, enc_W, dec_Wr, dec_Wz, dec_W, V_o};
    float*       Cs[7] = {XPr, XPz, XPc, YPr, YPz, YPc, YV};
    for (int i = 0; i < 7; ++i) { g.A[i] = As[i]; g.Bw[i] = Bs[i]; g.C[i] = Cs[i]; }
    g.lda = E_; g.ldb = E_; g.ldc = H_;
    g.M = S_ * B_; g.N = H_; g.K = E_; g.mode = 0;
    gemm_abT<<<dim3(16, 12, 7), dim3(256), 0, stream>>>(g);
  }

  // encoder recurrence
  for (int s = 0; s < S_; ++s) {
    gru_phaseA<<<dim3(250), dim3(256), 0, stream>>>(
        hbk, enc_Ur, enc_Uz, XPr + s * 32000, XPz + s * 32000,
        nullptr, nullptr, enc_br, enc_bz, rhbk, zb);
    gru_phaseB<<<dim3(250), dim3(256), 0, stream>>>(
        rhbk, enc_U, XPc + s * 32000, nullptr, enc_b, zb, hbk, nullptr);
  }

  // context projections + s0 (x = final encoder state hbk)
  {
    CtxArgs a = {};
    const float* Wm[5] = {dec_Cr, dec_Cz, dec_C, C_o, W_s};
    float* Om[5] = {cCr, cCz, cC, cCo, nullptr};
    int md[5] = {0, 0, 0, 0, 2};
    for (int i = 0; i < 5; ++i) { a.W[i] = Wm[i]; a.out[i] = Om[i]; a.mode[i] = md[i]; }
    a.x = hbk; a.hbk2 = hbk2; a.srm0 = Srm;
    ctx_mv<<<dim3(250, 1, 5), dim3(256), 0, stream>>>(a);
  }

  // decoder recurrence (23 updates produce s_1..s_23; s_t stored row-major in Srm)
  for (int t = 0; t < T_ - 1; ++t) {
    gru_phaseA<<<dim3(250), dim3(256), 0, stream>>>(
        hbk2, dec_Ur, dec_Uz, YPr + t * 32000, YPz + t * 32000,
        cCr, cCz, dec_br, dec_bz, rhbk, zb);
    gru_phaseB<<<dim3(250), dim3(256), 0, stream>>>(
        rhbk, dec_U, YPc + t * 32000, cC, dec_b, zb, hbk2, Srm + (t + 1) * 32000);
  }

  // t = S@U_o^T + YV + cCo, maxout -> Tmax [768][512-strided, 500 cols]
  {
    GemmArgs g = {};
    g.A[0] = Srm; g.Bw[0] = U_o; g.C[0] = Tmax;
    g.lda = H_; g.ldb = H_; g.ldc = 512;
    g.M = T_ * B_; g.N = M2_; g.K = H_; g.mode = 2;
    g.e1 = YV; g.e2 = cCo;
    gemm_abT<<<dim3(16, 12, 1), dim3(256), 0, stream>>>(g);
  }

  // logits = Tmax @ W_o^T, scatter to out[b][t][v]
  {
    GemmArgs g = {};
    g.A[0] = Tmax; g.Bw[0] = W_o; g.C[0] = out;
    g.lda = 512; g.ldb = MD_; g.ldc = V_;
    g.M = T_ * B_; g.N = V_; g.K = MD_; g.mode = 3;
    gemm_abT<<<dim3(469, 12, 1), dim3(256), 0, stream>>>(g);
  }
}

// Round 2
// 1891.758 us; speedup vs baseline: 1.4131x; 1.4131x over previous
//
#include <hip/hip_runtime.h>
#include <math.h>

typedef unsigned short ushort;
typedef unsigned int uint;
typedef __attribute__((ext_vector_type(8))) short bf16x8;
typedef __attribute__((ext_vector_type(4))) float f32x4;

#define B_  32
#define S_  24
#define T_  24
#define E_  620
#define EP_ 640
#define H_  1000
#define HP_ 1024
#define V_  30000
#define M2_ 1000
#define KW_ 512

__device__ __forceinline__ ushort f2bf(float f) {
  uint u = __float_as_uint(f);
  u += 0x7FFFu + ((u >> 16) & 1u);
  return (ushort)(u >> 16);
}
__device__ __forceinline__ float bf2f(ushort s) {
  return __uint_as_float(((uint)s) << 16);
}

// ---------------------------------------------------------------------------
// weight conversion: fp32 [N][K] -> bf16 [N][Kp] zero-padded
// ---------------------------------------------------------------------------
struct ConvJobs {
  const float* in[19];
  ushort* out[19];
  int K[19], Kp[19];
};
__global__ __launch_bounds__(256) void conv_small(ConvJobs a) {
  int j = blockIdx.y, row = blockIdx.x;
  const float* ip = a.in[j] + (size_t)row * a.K[j];
  ushort* op = a.out[j] + (size_t)row * a.Kp[j];
  for (int k = threadIdx.x; k < a.Kp[j]; k += 256)
    op[k] = (k < a.K[j]) ? f2bf(ip[k]) : (ushort)0;
}

__global__ __launch_bounds__(256) void conv_wo(const float* __restrict__ in,
                                               ushort* __restrict__ out) {
  int row = blockIdx.x;
  const float* ip = in + (size_t)row * 500;
  ushort* op = out + (size_t)row * 512;
  int k = threadIdx.x;
  op[k] = (k < 500) ? f2bf(ip[k]) : (ushort)0;
  k += 256;
  op[k] = (k < 500) ? f2bf(ip[k]) : (ushort)0;
}

// ---------------------------------------------------------------------------
// embedding gather -> bf16, K padded 620->640
// ---------------------------------------------------------------------------
__global__ __launch_bounds__(256) void gather16(
    const int* __restrict__ src, const int* __restrict__ tgt,
    const float* __restrict__ semb, const float* __restrict__ temb,
    ushort* __restrict__ XE, ushort* __restrict__ YE) {
  int row = blockIdx.x;
  int isT = row >= S_ * B_;
  int r = isT ? row - S_ * B_ : row;
  int st = r >> 5, b = r & 31;
  int tok = isT ? tgt[b * T_ + st] : src[b * S_ + st];
  const float* e = (isT ? temb : semb) + (size_t)tok * E_;
  ushort* o = (isT ? YE : XE) + (size_t)r * EP_;
  for (int k = threadIdx.x; k < EP_; k += 256)
    o[k] = (k < E_) ? f2bf(e[k]) : (ushort)0;
}

// ---------------------------------------------------------------------------
// bf16 MFMA GEMM: C = A @ Bw^T. A [M][Kp] bf16, Bw [N][Kp] bf16.
// 128x128 tile, 4 waves, each 64x64 (4x4 frags of 16x16x32).
// mode 0: fp32 store C[row][col] (ldc)
// mode 1: maxout: v = acc+e1[row][col]+e2[row&31][col]; pair-max -> bf16 tmax[row][col/2]
// mode 2: scatter: row=t*32+b -> C[(b*T+t)*ldc + col]
// ---------------------------------------------------------------------------
struct MG {
  const ushort* A[8];
  const ushort* Bw[8];
  float* C[8];
  int M, N, Kp, ldc;
  int mode;
  const float* e1;
  const float* e2;
  ushort* tmax;
};

__global__ __launch_bounds__(256) void mgemm(MG g) {
  __shared__ ushort As[128 * 40];
  __shared__ ushort Bs[128 * 40];
  const int z = blockIdx.z;
  const ushort* __restrict__ A = g.A[z];
  const ushort* __restrict__ Bw = g.Bw[z];
  const int tid = threadIdx.x;
  const int wave = tid >> 6, lane = tid & 63;
  const int lm = lane & 15, kq = lane >> 4;
  const int wm = (wave >> 1) * 64, wn = (wave & 1) * 64;
  const int m0 = blockIdx.y * 128, n0 = blockIdx.x * 128;
  const int Kp = g.Kp;

  f32x4 acc[4][4];
#pragma unroll
  for (int i = 0; i < 4; ++i)
#pragma unroll
    for (int j = 0; j < 4; ++j) acc[i][j] = (f32x4){0.f, 0.f, 0.f, 0.f};

  const int row_s = tid >> 2, seg = tid & 3;

  for (int k0 = 0; k0 < Kp; k0 += 32) {
#pragma unroll
    for (int p = 0; p < 2; ++p) {
      int row = row_s + p * 64;
      int gm = m0 + row;
      uint4 va = make_uint4(0, 0, 0, 0);
      if (gm < g.M) va = *(const uint4*)(A + (size_t)gm * Kp + k0 + seg * 8);
      *(uint4*)&As[row * 40 + seg * 8] = va;
      int gn = n0 + row;
      uint4 vb = make_uint4(0, 0, 0, 0);
      if (gn < g.N) vb = *(const uint4*)(Bw + (size_t)gn * Kp + k0 + seg * 8);
      *(uint4*)&Bs[row * 40 + seg * 8] = vb;
    }
    __syncthreads();
    bf16x8 af[4], bfr[4];
#pragma unroll
    for (int i = 0; i < 4; ++i)
      af[i] = *(const bf16x8*)&As[(wm + i * 16 + lm) * 40 + kq * 8];
#pragma unroll
    for (int j = 0; j < 4; ++j)
      bfr[j] = *(const bf16x8*)&Bs[(wn + j * 16 + lm) * 40 + kq * 8];
#pragma unroll
    for (int i = 0; i < 4; ++i)
#pragma unroll
      for (int j = 0; j < 4; ++j)
        acc[i][j] = __builtin_amdgcn_mfma_f32_16x16x32_bf16(af[i], bfr[j], acc[i][j], 0, 0, 0);
    __syncthreads();
  }

#pragma unroll
  for (int i = 0; i < 4; ++i) {
    int grow = m0 + wm + i * 16 + kq * 4;
#pragma unroll
    for (int j = 0; j < 4; ++j) {
      int gcol = n0 + wn + j * 16 + lm;
#pragma unroll
      for (int r = 0; r < 4; ++r) {
        int row = grow + r;
        float v = acc[i][j][r];
        if (g.mode == 0) {
          if (row < g.M && gcol < g.N) g.C[z][(size_t)row * g.ldc + gcol] = v;
        } else if (g.mode == 1) {
          float vv = v;
          if (row < g.M && gcol < g.N)
            vv += g.e1[(size_t)row * M2_ + gcol] + g.e2[(size_t)(row & 31) * M2_ + gcol];
          float other = __shfl_xor(vv, 1);
          if ((lane & 1) == 0 && row < g.M && gcol < g.N)
            g.tmax[(size_t)row * KW_ + (gcol >> 1)] = f2bf(fmaxf(vv, other));
        } else {
          if (row < g.M && gcol < g.N) {
            int t = row >> 5, b = row & 31;
            g.C[z][((size_t)b * T_ + t) * (size_t)g.ldc + gcol] = v;
          }
        }
      }
    }
  }
}

// ---------------------------------------------------------------------------
// GRU phase A (bf16 weights, branch-free): pre_r=h@Ur^T, pre_z=h@Uz^T
// ---------------------------------------------------------------------------
__global__ __launch_bounds__(256) void gru_phaseA16(
    const float* __restrict__ hbk,
    const ushort* __restrict__ Ur, const ushort* __restrict__ Uz,
    const float* __restrict__ Xr, const float* __restrict__ Xz,
    const float* __restrict__ cr, const float* __restrict__ cz,
    const float* __restrict__ br, const float* __restrict__ bz,
    float* __restrict__ rhbk, float* __restrict__ zb) {
  __shared__ float red[4][4][2][32];
  const int tid = threadIdx.x;
  const int w = tid >> 6, lane = tid & 63;
  const int b = lane & 31, kh = lane >> 5;
  const int j0 = blockIdx.x * 4;
  const int kbase = w * 256 + kh * 128;
  const float4* h4 = (const float4*)(hbk + b * HP_ + kbase);
  float accr[4] = {0.f, 0.f, 0.f, 0.f}, accz[4] = {0.f, 0.f, 0.f, 0.f};
#pragma unroll
  for (int i = 0; i < 16; ++i) {
    float4 ha = h4[2 * i], hb = h4[2 * i + 1];
    float hv[8] = {ha.x, ha.y, ha.z, ha.w, hb.x, hb.y, hb.z, hb.w};
    int k = kbase + i * 8;
#pragma unroll
    for (int j = 0; j < 4; ++j) {
      bf16x8 u = *(const bf16x8*)(Ur + (size_t)(j0 + j) * HP_ + k);
      bf16x8 v = *(const bf16x8*)(Uz + (size_t)(j0 + j) * HP_ + k);
#pragma unroll
      for (int e = 0; e < 8; ++e) {
        accr[j] = fmaf(hv[e], bf2f((ushort)u[e]), accr[j]);
        accz[j] = fmaf(hv[e], bf2f((ushort)v[e]), accz[j]);
      }
    }
  }
  float pr[4], pz[4];
#pragma unroll
  for (int j = 0; j < 4; ++j) {
    pr[j] = accr[j] + __shfl_xor(accr[j], 32);
    pz[j] = accz[j] + __shfl_xor(accz[j], 32);
  }
  if (lane < 32) {
#pragma unroll
    for (int j = 0; j < 4; ++j) {
      red[w][j][0][b] = pr[j];
      red[w][j][1][b] = pz[j];
    }
  }
  __syncthreads();
  int eb = tid & 31, eg = (tid >> 5) & 1, ej = tid >> 6;
  float s = red[0][ej][eg][eb] + red[1][ej][eg][eb] + red[2][ej][eg][eb] + red[3][ej][eg][eb];
  int j = j0 + ej;
  int o = eb * H_ + j;
  if (eg == 0) {
    float pre = s + Xr[o] + br[j] + (cr ? cr[o] : 0.f);
    float r = 1.f / (1.f + expf(-pre));
    rhbk[eb * HP_ + j] = r * hbk[eb * HP_ + j];
  } else {
    float pre = s + Xz[o] + bz[j] + (cz ? cz[o] : 0.f);
    zb[o] = 1.f / (1.f + expf(-pre));
  }
}

// ---------------------------------------------------------------------------
// GRU phase B: cand = tanh(rh@U^T + Xc + cc + bb); s = (1-z)*s + z*cand
// ---------------------------------------------------------------------------
__global__ __launch_bounds__(256) void gru_phaseB16(
    const float* __restrict__ rhbk, const ushort* __restrict__ U,
    const float* __restrict__ Xc, const float* __restrict__ cc,
    const float* __restrict__ bb, const float* __restrict__ zb,
    float* s_state, ushort* srm16) {
  __shared__ float red[4][4][32];
  const int tid = threadIdx.x;
  const int w = tid >> 6, lane = tid & 63;
  const int b = lane & 31, kh = lane >> 5;
  const int j0 = blockIdx.x * 4;
  const int kbase = w * 256 + kh * 128;
  const float4* h4 = (const float4*)(rhbk + b * HP_ + kbase);
  float acc[4] = {0.f, 0.f, 0.f, 0.f};
#pragma unroll
  for (int i = 0; i < 16; ++i) {
    float4 ha = h4[2 * i], hb = h4[2 * i + 1];
    float hv[8] = {ha.x, ha.y, ha.z, ha.w, hb.x, hb.y, hb.z, hb.w};
    int k = kbase + i * 8;
#pragma unroll
    for (int j = 0; j < 4; ++j) {
      bf16x8 u = *(const bf16x8*)(U + (size_t)(j0 + j) * HP_ + k);
#pragma unroll
      for (int e = 0; e < 8; ++e)
        acc[j] = fmaf(hv[e], bf2f((ushort)u[e]), acc[j]);
    }
  }
  float p[4];
#pragma unroll
  for (int j = 0; j < 4; ++j) p[j] = acc[j] + __shfl_xor(acc[j], 32);
  if (lane < 32) {
#pragma unroll
    for (int j = 0; j < 4; ++j) red[w][j][b] = p[j];
  }
  __syncthreads();
  if (tid < 128) {
    int eb = tid & 31, ej = tid >> 5;
    float s = red[0][ej][eb] + red[1][ej][eb] + red[2][ej][eb] + red[3][ej][eb];
    int j = j0 + ej;
    int o = eb * H_ + j;
    float cand = tanhf(s + Xc[o] + bb[j] + (cc ? cc[o] : 0.f));
    float z = zb[o];
    float old = s_state[eb * HP_ + j];
    float nv = (1.f - z) * old + z * cand;
    s_state[eb * HP_ + j] = nv;
    if (srm16) srm16[eb * HP_ + j] = f2bf(nv);
  }
}

// ---------------------------------------------------------------------------
// context projections + s0 (bf16 weights)
// ---------------------------------------------------------------------------
struct Ctx16 {
  const ushort* W[5];
  float* out[5];
  int mode[5];
  const float* x;
  float* hbk2;
  ushort* srm0;
};

__global__ __launch_bounds__(256) void ctx_mv16(Ctx16 a) {
  __shared__ float red[4][4][32];
  const int z = blockIdx.z;
  const ushort* __restrict__ W = a.W[z];
  const float* __restrict__ x = a.x;
  const int tid = threadIdx.x;
  const int w = tid >> 6, lane = tid & 63;
  const int b = lane & 31, kh = lane >> 5;
  const int j0 = blockIdx.x * 4;
  const int kbase = w * 256 + kh * 128;
  const float4* h4 = (const float4*)(x + b * HP_ + kbase);
  float acc[4] = {0.f, 0.f, 0.f, 0.f};
#pragma unroll
  for (int i = 0; i < 16; ++i) {
    float4 ha = h4[2 * i], hb = h4[2 * i + 1];
    float hv[8] = {ha.x, ha.y, ha.z, ha.w, hb.x, hb.y, hb.z, hb.w};
    int k = kbase + i * 8;
#pragma unroll
    for (int j = 0; j < 4; ++j) {
      bf16x8 u = *(const bf16x8*)(W + (size_t)(j0 + j) * HP_ + k);
#pragma unroll
      for (int e = 0; e < 8; ++e)
        acc[j] = fmaf(hv[e], bf2f((ushort)u[e]), acc[j]);
    }
  }
  float p[4];
#pragma unroll
  for (int j = 0; j < 4; ++j) p[j] = acc[j] + __shfl_xor(acc[j], 32);
  if (lane < 32) {
#pragma unroll
    for (int j = 0; j < 4; ++j) red[w][j][b] = p[j];
  }
  __syncthreads();
  if (tid < 128) {
    int eb = tid & 31, ej = tid >> 5;
    float s = red[0][ej][eb] + red[1][ej][eb] + red[2][ej][eb] + red[3][ej][eb];
    int j = j0 + ej;
    if (a.mode[z] == 0) {
      a.out[z][eb * H_ + j] = s;
    } else {
      float v = tanhf(s);
      a.hbk2[eb * HP_ + j] = v;
      a.srm0[eb * HP_ + j] = f2bf(v);
    }
  }
}

// ---------------------------------------------------------------------------
// Host
// ---------------------------------------------------------------------------
extern "C" void kernel_launch(void* const* d_in, const int* in_sizes, int n_in,
                              void* d_out, int out_size, void* d_ws, size_t ws_size,
                              hipStream_t stream) {
  const int*   src     = (const int*)d_in[0];
  const int*   tgt     = (const int*)d_in[1];
  const float* src_emb = (const float*)d_in[3];
  const float* tgt_emb = (const float*)d_in[4];
  const float* enc_W   = (const float*)d_in[5];
  const float* enc_Wz  = (const float*)d_in[6];
  const float* enc_Wr  = (const float*)d_in[7];
  const float* enc_U   = (const float*)d_in[8];
  const float* enc_Uz  = (const float*)d_in[9];
  const float* enc_Ur  = (const float*)d_in[10];
  const float* enc_b   = (const float*)d_in[11];
  const float* enc_bz  = (const float*)d_in[12];
  const float* enc_br  = (const float*)d_in[13];
  const float* dec_W   = (const float*)d_in[14];
  const float* dec_Wz  = (const float*)d_in[15];
  const float* dec_Wr  = (const float*)d_in[16];
  const float* dec_U   = (const float*)d_in[17];
  const float* dec_Uz  = (const float*)d_in[18];
  const float* dec_Ur  = (const float*)d_in[19];
  const float* dec_C   = (const float*)d_in[20];
  const float* dec_Cz  = (const float*)d_in[21];
  const float* dec_Cr  = (const float*)d_in[22];
  const float* dec_b   = (const float*)d_in[23];
  const float* dec_bz  = (const float*)d_in[24];
  const float* dec_br  = (const float*)d_in[25];
  const float* W_s     = (const float*)d_in[26];
  const float* U_o     = (const float*)d_in[27];
  const float* V_o     = (const float*)d_in[28];
  const float* C_o     = (const float*)d_in[29];
  const float* W_o     = (const float*)d_in[30];
  float* out = (float*)d_out;
  char* wsb = (char*)d_ws;
  (void)in_sizes; (void)n_in; (void)out_size; (void)ws_size;

  // byte-offset workspace layout
  float*  hbk   = (float*)(wsb + 0);         // 32x1024
  float*  rhbk  = (float*)(wsb + 131072);
  float*  hbk2  = (float*)(wsb + 262144);
  ushort* Srm16 = (ushort*)(wsb + 393216);   // 768x1024 bf16
  ushort* Tmax  = (ushort*)(wsb + 1966080);  // 768x512 bf16
  // zero block ends at 2752512
  float*  zb    = (float*)(wsb + 2752512);   // 32x1000
  float*  cCr   = (float*)(wsb + 2880512);
  float*  cCz   = (float*)(wsb + 3008512);
  float*  cC    = (float*)(wsb + 3136512);
  float*  cCo   = (float*)(wsb + 3264512);
  float*  YV    = (float*)(wsb + 3392512);   // 768x1000
  float*  XPr   = (float*)(wsb + 6464512);
  float*  XPz   = (float*)(wsb + 9536512);
  float*  XPc   = (float*)(wsb + 12608512);
  float*  YPr   = (float*)(wsb + 15680512);
  float*  YPz   = (float*)(wsb + 18752512);
  float*  YPc   = (float*)(wsb + 21824512);
  ushort* XE16  = (ushort*)(wsb + 24896512); // 768x640 bf16
  ushort* YE16  = (ushort*)(wsb + 25879552);
  ushort* H16   = (ushort*)(wsb + 26862592); // 12 x 1000x1024 bf16
  ushort* E16   = (ushort*)(wsb + 51438592); // 7 x 1000x640 bf16
  ushort* Wo16  = (ushort*)(wsb + 60398592); // 30000x512 bf16

  // zero: state buffers + Srm16 pads + Tmax pads
  hipMemsetAsync(wsb, 0, 2752512, stream);

  // ---- weight conversions (per call; ws is re-poisoned每 call) ----
  {
    ConvJobs a = {};
    const float* hin[12] = {enc_Ur, enc_Uz, enc_U, dec_Ur, dec_Uz, dec_U,
                            dec_Cr, dec_Cz, dec_C, C_o, W_s, U_o};
    const float* ein[7]  = {enc_Wr, enc_Wz, enc_W, dec_Wr, dec_Wz, dec_W, V_o};
    for (int i = 0; i < 12; ++i) {
      a.in[i] = hin[i]; a.out[i] = H16 + (size_t)i * 1000 * HP_;
      a.K[i] = H_; a.Kp[i] = HP_;
    }
    for (int i = 0; i < 7; ++i) {
      a.in[12 + i] = ein[i]; a.out[12 + i] = E16 + (size_t)i * 1000 * EP_;
      a.K[12 + i] = E_; a.Kp[12 + i] = EP_;
    }
    conv_small<<<dim3(1000, 19), dim3(256), 0, stream>>>(a);
  }
  conv_wo<<<dim3(V_), dim3(256), 0, stream>>>(W_o, Wo16);

  gather16<<<dim3(2 * S_ * B_), dim3(256), 0, stream>>>(src, tgt, src_emb, tgt_emb, XE16, YE16);

  // ---- batched input projections (MFMA): M=768 N=1000 Kp=640 ----
  {
    MG g = {};
    const ushort* As[7] = {XE16, XE16, XE16, YE16, YE16, YE16, YE16};
    float* Cs[7] = {XPr, XPz, XPc, YPr, YPz, YPc, YV};
    for (int i = 0; i < 7; ++i) {
      g.A[i] = As[i]; g.Bw[i] = E16 + (size_t)i * 1000 * EP_; g.C[i] = Cs[i];
    }
    g.M = S_ * B_; g.N = H_; g.Kp = EP_; g.ldc = H_; g.mode = 0;
    mgemm<<<dim3(8, 6, 7), dim3(256), 0, stream>>>(g);
  }

  const ushort* encUr16 = H16 + 0 * 1024000;
  const ushort* encUz16 = H16 + 1 * 1024000;
  const ushort* encU16  = H16 + 2 * 1024000;
  const ushort* decUr16 = H16 + 3 * 1024000;
  const ushort* decUz16 = H16 + 4 * 1024000;
  const ushort* decU16  = H16 + 5 * 1024000;
  const ushort* Uo16    = H16 + 11 * 1024000;

  // ---- encoder recurrence ----
  for (int s = 0; s < S_; ++s) {
    gru_phaseA16<<<dim3(250), dim3(256), 0, stream>>>(
        hbk, encUr16, encUz16, XPr + s * 32000, XPz + s * 32000,
        nullptr, nullptr, enc_br, enc_bz, rhbk, zb);
    gru_phaseB16<<<dim3(250), dim3(256), 0, stream>>>(
        rhbk, encU16, XPc + s * 32000, nullptr, enc_b, zb, hbk, nullptr);
  }

  // ---- context projections + s0 ----
  {
    Ctx16 a = {};
    for (int i = 0; i < 5; ++i) {
      a.W[i] = H16 + (size_t)(6 + i) * 1024000;
      a.mode[i] = (i == 4) ? 2 : 0;
    }
    a.out[0] = cCr; a.out[1] = cCz; a.out[2] = cC; a.out[3] = cCo; a.out[4] = nullptr;
    a.x = hbk; a.hbk2 = hbk2; a.srm0 = Srm16;
    ctx_mv16<<<dim3(250, 1, 5), dim3(256), 0, stream>>>(a);
  }

  // ---- decoder recurrence ----
  for (int t = 0; t < T_ - 1; ++t) {
    gru_phaseA16<<<dim3(250), dim3(256), 0, stream>>>(
        hbk2, decUr16, decUz16, YPr + t * 32000, YPz + t * 32000,
        cCr, cCz, dec_br, dec_bz, rhbk, zb);
    gru_phaseB16<<<dim3(250), dim3(256), 0, stream>>>(
        rhbk, decU16, YPc + t * 32000, cC, dec_b, zb, hbk2,
        Srm16 + (size_t)(t + 1) * B_ * HP_);
  }

  // ---- maxout GEMM: t = Srm@U_o^T + YV + cCo -> Tmax bf16 [768][512] ----
  {
    MG g = {};
    g.A[0] = Srm16; g.Bw[0] = Uo16;
    g.M = T_ * B_; g.N = M2_; g.Kp = HP_; g.ldc = 0; g.mode = 1;
    g.e1 = YV; g.e2 = cCo; g.tmax = Tmax;
    mgemm<<<dim3(8, 6, 1), dim3(256), 0, stream>>>(g);
  }

  // ---- logits = Tmax @ W_o^T -> out[b][t][v] ----
  {
    MG g = {};
    g.A[0] = Tmax; g.Bw[0] = Wo16; g.C[0] = out;
    g.M = T_ * B_; g.N = V_; g.Kp = KW_; g.ldc = V_; g.mode = 2;
    mgemm<<<dim3(235, 6, 1), dim3(256), 0, stream>>>(g);
  }
}